// Round 4
// baseline (731.878 us; speedup 1.0000x reference)
//
#include <hip/hip_runtime.h>

#define N_NODES 100000
#define N_EDGES 1600000
#define N_GRAPHS 256
#define F_IN 38
#define F_PAD 40   // x packed to 40 bf16 (80 B rows); 20 uints per row
#define HID 64
#define CAP 64     // per-node incoming-edge slot capacity (Poisson(16), max ~45)

typedef unsigned int uint;

__device__ __forceinline__ float blo(uint v) {
    union { uint i; float f; } u; u.i = v << 16; return u.f;
}
__device__ __forceinline__ float bhi(uint v) {
    union { uint i; float f; } u; u.i = v & 0xFFFF0000u; return u.f;
}
__device__ __forceinline__ unsigned short f2b(float f) {
    union { float f; uint i; } v; v.f = f;
    uint lsb = (v.i >> 16) & 1u;
    return (unsigned short)((v.i + 0x7fffu + lsb) >> 16);
}

// ---------------------------------------------------------------------------
// Pack x [N][38] fp32 -> xb [N+1][40] bf16 (zero-padded cols; row N all-zero)
// ---------------------------------------------------------------------------
__global__ void pack_x_kernel(const float* __restrict__ x,
                              unsigned short* __restrict__ xb) {
    int tid = blockIdx.x * blockDim.x + threadIdx.x;
    if (tid >= (N_NODES + 1) * F_PAD) return;
    int n = tid / F_PAD;
    int f = tid - n * F_PAD;
    float v = (n < N_NODES && f < F_IN) ? x[n * F_IN + f] : 0.0f;
    xb[tid] = f2b(v);
}

// ---------------------------------------------------------------------------
// Bucket-CSR: slots[d*64+pos] = src, cnt[d] = in-degree
// ---------------------------------------------------------------------------
__global__ void csr_build_kernel(const int* __restrict__ src,
                                 const int* __restrict__ dst,
                                 int* __restrict__ cnt,
                                 int* __restrict__ slots) {
    int e = blockIdx.x * blockDim.x + threadIdx.x;
    if (e >= N_EDGES) return;
    int d = dst[e];
    int pos = atomicAdd(&cnt[d], 1);
    if (pos < CAP) slots[(d << 6) + pos] = src[e];
}

// ---------------------------------------------------------------------------
// Pad each node's slots to a multiple of 16 with dummy index N_NODES (whose
// xb/hb rows are all-zero). Also zero the hb dummy row. cntp = padded degree.
// ---------------------------------------------------------------------------
__global__ void pad_slots_kernel(const int* __restrict__ cnt,
                                 int* __restrict__ cntp,
                                 int* __restrict__ slots,
                                 unsigned short* __restrict__ hb) {
    int n = blockIdx.x * blockDim.x + threadIdx.x;
    if (n < HID) hb[(N_NODES << 6) + n] = 0;   // hb dummy row = 0
    if (n >= N_NODES) return;
    int deg = cnt[n]; if (deg > CAP) deg = CAP;
    int dp = (deg + 15) & ~15;
    if (dp > CAP) dp = CAP;
    for (int k = deg; k < dp; ++k) slots[(n << 6) + k] = N_NODES;
    cntp[n] = dp;
}

// ---------------------------------------------------------------------------
// Layer 1 fused: half-wave bf16x2 gather (16 rows in flight), dense from LDS,
// relu -> hb (bf16), per-graph h-sum pooling. LDS ~38.5 KB -> 4 blocks/CU.
// ---------------------------------------------------------------------------
__global__ __launch_bounds__(256, 4) void layer1_kernel(
        const float* __restrict__ x,
        const unsigned short* __restrict__ xb,
        const int* __restrict__ cntp,
        const int* __restrict__ slots,
        const float* __restrict__ w_rel,
        const float* __restrict__ b_rel,
        const float* __restrict__ w_root,
        const int* __restrict__ batch,
        unsigned short* __restrict__ hb,
        float* __restrict__ hsum) {
    __shared__ float s_wrel[F_IN * HID];    // 9.5 KB
    __shared__ float s_wroot[F_IN * HID];   // 9.5 KB
    __shared__ float s_a[64][F_PAD];        // 10 KB
    __shared__ float s_x[64][F_IN];         // 9.5 KB
    for (int i = threadIdx.x; i < F_IN * HID; i += 256) {
        s_wrel[i] = w_rel[i];
        s_wroot[i] = w_root[i];
    }
    const int wave = threadIdx.x >> 6, lane = threadIdx.x & 63;
    const int half = lane >> 5, l2 = lane & 31;
    const int base = blockIdx.x * 64;
    const uint* xb32 = (const uint*)xb;     // 20 uints per row

    for (int i = 0; i < 16; ++i) {
        int nl = wave * 16 + i;
        int n = base + nl;
        if (n < N_NODES && lane < F_IN) s_x[nl][lane] = x[n * F_IN + lane];
        float sx = 0.f, sy = 0.f;
        int dp = (n < N_NODES) ? cntp[n] : 0;
        const int* sl = slots + (n << 6) + (half << 3);
        for (int j = 0; j < dp; j += 16) {
            int4 a4 = *(const int4*)(sl + j);
            int4 b4 = *(const int4*)(sl + j + 4);
            if (l2 < 20) {
                uint v0 = xb32[a4.x * 20 + l2];
                uint v1 = xb32[a4.y * 20 + l2];
                uint v2 = xb32[a4.z * 20 + l2];
                uint v3 = xb32[a4.w * 20 + l2];
                uint v4 = xb32[b4.x * 20 + l2];
                uint v5 = xb32[b4.y * 20 + l2];
                uint v6 = xb32[b4.z * 20 + l2];
                uint v7 = xb32[b4.w * 20 + l2];
                sx += blo(v0) + blo(v1) + blo(v2) + blo(v3)
                    + blo(v4) + blo(v5) + blo(v6) + blo(v7);
                sy += bhi(v0) + bhi(v1) + bhi(v2) + bhi(v3)
                    + bhi(v4) + bhi(v5) + bhi(v6) + bhi(v7);
            }
        }
        sx += __shfl_down(sx, 32);
        sy += __shfl_down(sy, 32);
        if (half == 0 && l2 < 20) {
            s_a[nl][2 * l2]     = sx;
            s_a[nl][2 * l2 + 1] = sy;
        }
    }
    __syncthreads();

    const int c = lane, r = wave;
    const float bias = b_rel[c];
    float psum = 0.f;
    int cur_g = -1;
    for (int i = 0; i < 16; ++i) {
        int nl = r * 16 + i;
        int n = base + nl;
        if (n >= N_NODES) break;
        float acc = bias;
        #pragma unroll
        for (int k = 0; k < F_IN; ++k) {
            acc += s_a[nl][k] * s_wrel[k * HID + c];
            acc += s_x[nl][k] * s_wroot[k * HID + c];
        }
        float hv = fmaxf(acc, 0.f);
        hb[(n << 6) + c] = f2b(hv);
        int g = batch[n];
        if (g != cur_g) {
            if (cur_g >= 0) atomicAdd(&hsum[(cur_g << 6) + c], psum);
            psum = 0.f;
            cur_g = g;
        }
        psum += hv;
    }
    if (cur_g >= 0) atomicAdd(&hsum[(cur_g << 6) + c], psum);
}

// ---------------------------------------------------------------------------
// Layer 2 rel-half: half-wave bf16x2 gather of hb rows (16 rows in flight),
// agg2 @ w2_rel, per-graph pooling. LDS 32 KB -> 5 blocks/CU (62.5% occ).
// ---------------------------------------------------------------------------
__global__ __launch_bounds__(256, 5) void layer2_kernel(
        const unsigned short* __restrict__ hb,
        const int* __restrict__ cntp,
        const int* __restrict__ slots,
        const float* __restrict__ w_rel,
        const int* __restrict__ batch,
        float* __restrict__ pooled_rel) {
    __shared__ float s_wrel[HID * HID];     // 16 KB
    __shared__ float s_a[64][HID];          // 16 KB
    for (int i = threadIdx.x; i < HID * HID; i += 256) s_wrel[i] = w_rel[i];
    const int wave = threadIdx.x >> 6, lane = threadIdx.x & 63;
    const int half = lane >> 5, l2 = lane & 31;
    const int base = blockIdx.x * 64;
    const uint* hb32 = (const uint*)hb;     // 32 uints per row

    for (int i = 0; i < 16; ++i) {
        int nl = wave * 16 + i;
        int n = base + nl;
        float sx = 0.f, sy = 0.f;
        int dp = (n < N_NODES) ? cntp[n] : 0;
        const int* sl = slots + (n << 6) + (half << 3);
        for (int j = 0; j < dp; j += 16) {
            int4 a4 = *(const int4*)(sl + j);
            int4 b4 = *(const int4*)(sl + j + 4);
            uint v0 = hb32[(a4.x << 5) + l2];
            uint v1 = hb32[(a4.y << 5) + l2];
            uint v2 = hb32[(a4.z << 5) + l2];
            uint v3 = hb32[(a4.w << 5) + l2];
            uint v4 = hb32[(b4.x << 5) + l2];
            uint v5 = hb32[(b4.y << 5) + l2];
            uint v6 = hb32[(b4.z << 5) + l2];
            uint v7 = hb32[(b4.w << 5) + l2];
            sx += blo(v0) + blo(v1) + blo(v2) + blo(v3)
                + blo(v4) + blo(v5) + blo(v6) + blo(v7);
            sy += bhi(v0) + bhi(v1) + bhi(v2) + bhi(v3)
                + bhi(v4) + bhi(v5) + bhi(v6) + bhi(v7);
        }
        sx += __shfl_down(sx, 32);
        sy += __shfl_down(sy, 32);
        if (half == 0) {
            s_a[nl][2 * l2]     = sx;
            s_a[nl][2 * l2 + 1] = sy;
        }
    }
    __syncthreads();

    const int c = lane, r = wave;
    float psum = 0.f;
    int cur_g = -1;
    for (int i = 0; i < 16; ++i) {
        int nl = r * 16 + i;
        int n = base + nl;
        if (n >= N_NODES) break;
        float acc = 0.f;
        #pragma unroll
        for (int k = 0; k < HID; ++k) acc += s_a[nl][k] * s_wrel[k * HID + c];
        int g = batch[n];
        if (g != cur_g) {
            if (cur_g >= 0) atomicAdd(&pooled_rel[(cur_g << 6) + c], psum);
            psum = 0.f;
            cur_g = g;
        }
        psum += acc;
    }
    if (cur_g >= 0) atomicAdd(&pooled_rel[(cur_g << 6) + c], psum);
}

// ---------------------------------------------------------------------------
// out[g][c] = relu( (pooled_rel + hsum@w2_root + cnt*b2) / max(cnt,1) )
// ---------------------------------------------------------------------------
__global__ void finalize_kernel(const float* __restrict__ pooled_rel,
                                const float* __restrict__ hsum,
                                const float* __restrict__ w2_root,
                                const float* __restrict__ b2,
                                const int* __restrict__ batch,
                                float* __restrict__ out) {
    __shared__ float s_h[HID];
    const int g = blockIdx.x;
    const int c = threadIdx.x;
    s_h[c] = hsum[(g << 6) + c];
    __syncthreads();

    int lo = 0, hi = N_NODES;
    while (lo < hi) { int m = (lo + hi) >> 1; if (batch[m] < g) lo = m + 1; else hi = m; }
    int start = lo;
    hi = N_NODES;
    while (lo < hi) { int m = (lo + hi) >> 1; if (batch[m] < g + 1) lo = m + 1; else hi = m; }
    int cntg = lo - start;

    float acc = pooled_rel[(g << 6) + c] + (float)cntg * b2[c];
    #pragma unroll
    for (int k = 0; k < HID; ++k) acc += s_h[k] * w2_root[k * HID + c];
    float denom = cntg > 0 ? (float)cntg : 1.f;
    out[(g << 6) + c] = fmaxf(acc / denom, 0.f);
}

// ---------------------------------------------------------------------------
extern "C" void kernel_launch(void* const* d_in, const int* in_sizes, int n_in,
                              void* d_out, int out_size, void* d_ws, size_t ws_size,
                              hipStream_t stream) {
    const float* x       = (const float*)d_in[0];
    const int*   ei      = (const int*)  d_in[1];
    const int*   batch   = (const int*)  d_in[2];
    const float* w1_rel  = (const float*)d_in[3];
    const float* b1_rel  = (const float*)d_in[4];
    const float* w1_root = (const float*)d_in[5];
    const float* w2_rel  = (const float*)d_in[6];
    const float* b2_rel  = (const float*)d_in[7];
    const float* w2_root = (const float*)d_in[8];
    float* out = (float*)d_out;

    const int* src = ei;
    const int* dst = ei + N_EDGES;

    // ws layout (bytes):
    //   [0,       400000)  cnt        N int          (zeroed)
    //   [400000,  465536)  hsum       256*64 f32     (zeroed)
    //   [465536,  531072)  pooled_rel 256*64 f32     (zeroed)
    //   [531072,  931072)  cntp       N int
    //   [931072, 26531072) slots      N*64 int       (16B-aligned)
    //   [26531072,34531152) xb        (N+1)*40 bf16
    //   [34531152,47331280) hb        (N+1)*64 bf16
    char* wsb = (char*)d_ws;
    int*            cnt        = (int*)           (wsb);
    float*          hsum       = (float*)         (wsb + 400000);
    float*          pooled_rel = (float*)         (wsb + 465536);
    int*            cntp       = (int*)           (wsb + 531072);
    int*            slots      = (int*)           (wsb + 931072);
    unsigned short* xb         = (unsigned short*)(wsb + 26531072);
    unsigned short* hb         = (unsigned short*)(wsb + 34531152);

    hipMemsetAsync(wsb, 0, 531072, stream);

    {   // pack x -> bf16 [N+1][40]
        int total = (N_NODES + 1) * F_PAD;
        pack_x_kernel<<<(total + 255) / 256, 256, 0, stream>>>(x, xb);
    }
    {   // CSR build
        csr_build_kernel<<<(N_EDGES + 255) / 256, 256, 0, stream>>>(src, dst, cnt, slots);
    }
    {   // pad slots to multiple of 16 with dummy; zero hb dummy row
        pad_slots_kernel<<<(N_NODES + 255) / 256, 256, 0, stream>>>(cnt, cntp, slots, hb);
    }
    {   // layer 1
        int blocks = (N_NODES + 63) / 64;
        layer1_kernel<<<blocks, 256, 0, stream>>>(x, xb, cntp, slots, w1_rel, b1_rel,
                                                  w1_root, batch, hb, hsum);
    }
    {   // layer 2 rel-half
        int blocks = (N_NODES + 63) / 64;
        layer2_kernel<<<blocks, 256, 0, stream>>>(hb, cntp, slots, w2_rel, batch,
                                                  pooled_rel);
    }
    {   // finalize
        finalize_kernel<<<N_GRAPHS, HID, 0, stream>>>(pooled_rel, hsum, w2_root,
                                                      b2_rel, batch, out);
    }
}

// Round 5
// 472.226 us; speedup vs baseline: 1.5498x; 1.5498x over previous
//
#include <hip/hip_runtime.h>

#define N_NODES 100000
#define N_EDGES 1600000
#define N_GRAPHS 256
#define F_IN 38
#define F_PAD 40   // x packed to 40 bf16 (80 B rows)
#define HID 64
#define CAP 64     // per-node incoming-edge slot capacity (Poisson(16), max ~45)

typedef unsigned short ushort;
typedef unsigned int uint;

__device__ __forceinline__ float b2f(ushort u) {
    union { uint i; float f; } v; v.i = ((uint)u) << 16; return v.f;
}
__device__ __forceinline__ ushort f2b(float f) {
    union { float f; uint i; } v; v.f = f;
    uint lsb = (v.i >> 16) & 1u;
    return (ushort)((v.i + 0x7fffu + lsb) >> 16);
}

// ---------------------------------------------------------------------------
// Pack x [N][38] fp32 -> xb [N+1][40] bf16 (zero-padded cols; row N all-zero)
// ---------------------------------------------------------------------------
__global__ void pack_x_kernel(const float* __restrict__ x,
                              ushort* __restrict__ xb) {
    int tid = blockIdx.x * blockDim.x + threadIdx.x;
    if (tid >= (N_NODES + 1) * F_PAD) return;
    int n = tid / F_PAD;
    int f = tid - n * F_PAD;
    float v = (n < N_NODES && f < F_IN) ? x[n * F_IN + f] : 0.0f;
    xb[tid] = f2b(v);
}

// ---------------------------------------------------------------------------
// Bucket-CSR: slots[d*64+pos] = src, cnt[d] = in-degree
// ---------------------------------------------------------------------------
__global__ void csr_build_kernel(const int* __restrict__ src,
                                 const int* __restrict__ dst,
                                 int* __restrict__ cnt,
                                 int* __restrict__ slots) {
    int e = blockIdx.x * blockDim.x + threadIdx.x;
    if (e >= N_EDGES) return;
    int d = dst[e];
    int pos = atomicAdd(&cnt[d], 1);
    if (pos < CAP) slots[(d << 6) + pos] = src[e];
}

// ---------------------------------------------------------------------------
// Pad each node's slots to a multiple of 16 with dummy index N_NODES (whose
// xb/hb rows are all-zero). Zero the hb dummy row. cntp = padded degree.
// ---------------------------------------------------------------------------
__global__ void pad_slots_kernel(const int* __restrict__ cnt,
                                 int* __restrict__ cntp,
                                 int* __restrict__ slots,
                                 ushort* __restrict__ hb) {
    int n = blockIdx.x * blockDim.x + threadIdx.x;
    if (n < HID) hb[(N_NODES << 6) + n] = 0;   // hb dummy row = 0
    if (n >= N_NODES) return;
    int deg = cnt[n]; if (deg > CAP) deg = CAP;
    int dp = (deg + 15) & ~15;
    if (dp > CAP) dp = CAP;
    for (int k = deg; k < dp; ++k) slots[(n << 6) + k] = N_NODES;
    cntp[n] = dp;
}

// ---------------------------------------------------------------------------
// Layer 1 fused: full-wave bf16 row gather (16 rows in flight, one segment
// per load instruction), dense from LDS (float4), relu -> hb (bf16),
// per-graph h-sum pooling. LDS 40 KB -> 4 blocks/CU.
// ---------------------------------------------------------------------------
__global__ __launch_bounds__(256, 4) void layer1_kernel(
        const float* __restrict__ x,
        const ushort* __restrict__ xb,
        const int* __restrict__ cntp,
        const int* __restrict__ slots,
        const float* __restrict__ w_rel,
        const float* __restrict__ b_rel,
        const float* __restrict__ w_root,
        const int* __restrict__ batch,
        ushort* __restrict__ hb,
        float* __restrict__ hsum) {
    __shared__ float s_wrel[F_PAD * HID];   // 10 KB (rows 38,39 = 0)
    __shared__ float s_wroot[F_PAD * HID];  // 10 KB
    __shared__ float s_a[64][F_PAD];        // 10 KB
    __shared__ float s_x[64][F_PAD];        // 10 KB
    for (int i = threadIdx.x; i < F_PAD * HID; i += 256) {
        float wr = 0.f, wo = 0.f;
        if (i < F_IN * HID) { wr = w_rel[i]; wo = w_root[i]; }
        s_wrel[i] = wr;
        s_wroot[i] = wo;
    }
    const int wave = threadIdx.x >> 6, lane = threadIdx.x & 63;
    const int base = blockIdx.x * 64;

    // Phase A: 16 row-loads in flight per wave; remainder-free (padded)
    for (int i = 0; i < 16; ++i) {
        int nl = wave * 16 + i;
        int n = base + nl;
        float xv = 0.f;
        int dp = 0;
        if (n < N_NODES) {
            dp = cntp[n];
            if (lane < F_IN) xv = x[n * F_IN + lane];
        }
        float sum = 0.f;
        const int* sl = slots + (n << 6);
        for (int j = 0; j < dp; j += 16) {
            int4 a4 = *(const int4*)(sl + j);
            int4 b4 = *(const int4*)(sl + j + 4);
            int4 c4 = *(const int4*)(sl + j + 8);
            int4 d4 = *(const int4*)(sl + j + 12);
            if (lane < F_PAD) {
                float t0 = b2f(xb[a4.x * F_PAD + lane]);
                float t1 = b2f(xb[a4.y * F_PAD + lane]);
                float t2 = b2f(xb[a4.z * F_PAD + lane]);
                float t3 = b2f(xb[a4.w * F_PAD + lane]);
                float t4 = b2f(xb[b4.x * F_PAD + lane]);
                float t5 = b2f(xb[b4.y * F_PAD + lane]);
                float t6 = b2f(xb[b4.z * F_PAD + lane]);
                float t7 = b2f(xb[b4.w * F_PAD + lane]);
                float t8 = b2f(xb[c4.x * F_PAD + lane]);
                float t9 = b2f(xb[c4.y * F_PAD + lane]);
                float ta = b2f(xb[c4.z * F_PAD + lane]);
                float tb = b2f(xb[c4.w * F_PAD + lane]);
                float tc = b2f(xb[d4.x * F_PAD + lane]);
                float td = b2f(xb[d4.y * F_PAD + lane]);
                float te = b2f(xb[d4.z * F_PAD + lane]);
                float tf = b2f(xb[d4.w * F_PAD + lane]);
                sum += ((t0 + t1) + (t2 + t3)) + ((t4 + t5) + (t6 + t7))
                     + ((t8 + t9) + (ta + tb)) + ((tc + td) + (te + tf));
            }
        }
        if (lane < F_PAD) {
            s_a[nl][lane] = sum;
            s_x[nl][lane] = xv;   // cols 38,39: xv==0
        }
    }
    __syncthreads();

    // Phase B: dense from LDS (float4 reads) + bf16 store + pooling
    const int c = lane, r = wave;
    const float bias = b_rel[c];
    float psum = 0.f;
    int cur_g = -1;
    for (int i = 0; i < 16; ++i) {
        int nl = r * 16 + i;
        int n = base + nl;
        if (n >= N_NODES) break;
        float acc = bias;
        #pragma unroll
        for (int k = 0; k < F_PAD; k += 4) {
            float4 av = *(const float4*)&s_a[nl][k];
            float4 xv = *(const float4*)&s_x[nl][k];
            acc += av.x * s_wrel[(k + 0) * HID + c] + av.y * s_wrel[(k + 1) * HID + c]
                 + av.z * s_wrel[(k + 2) * HID + c] + av.w * s_wrel[(k + 3) * HID + c];
            acc += xv.x * s_wroot[(k + 0) * HID + c] + xv.y * s_wroot[(k + 1) * HID + c]
                 + xv.z * s_wroot[(k + 2) * HID + c] + xv.w * s_wroot[(k + 3) * HID + c];
        }
        float hv = fmaxf(acc, 0.f);
        hb[(n << 6) + c] = f2b(hv);
        int g = batch[n];
        if (g != cur_g) {
            if (cur_g >= 0) atomicAdd(&hsum[(cur_g << 6) + c], psum);
            psum = 0.f;
            cur_g = g;
        }
        psum += hv;
    }
    if (cur_g >= 0) atomicAdd(&hsum[(cur_g << 6) + c], psum);
}

// ---------------------------------------------------------------------------
// Layer 2 rel-half: full-wave bf16 row gather of hb (16 rows in flight),
// agg2 @ w2_rel (float4 LDS reads), per-graph pooling. LDS 32 KB.
// ---------------------------------------------------------------------------
__global__ __launch_bounds__(256, 4) void layer2_kernel(
        const ushort* __restrict__ hb,
        const int* __restrict__ cntp,
        const int* __restrict__ slots,
        const float* __restrict__ w_rel,
        const int* __restrict__ batch,
        float* __restrict__ pooled_rel) {
    __shared__ float s_wrel[HID * HID];     // 16 KB
    __shared__ float s_a[64][HID];          // 16 KB
    for (int i = threadIdx.x; i < HID * HID; i += 256) s_wrel[i] = w_rel[i];
    const int wave = threadIdx.x >> 6, lane = threadIdx.x & 63;
    const int base = blockIdx.x * 64;

    for (int i = 0; i < 16; ++i) {
        int nl = wave * 16 + i;
        int n = base + nl;
        int dp = (n < N_NODES) ? cntp[n] : 0;
        float sum = 0.f;
        const int* sl = slots + (n << 6);
        for (int j = 0; j < dp; j += 16) {
            int4 a4 = *(const int4*)(sl + j);
            int4 b4 = *(const int4*)(sl + j + 4);
            int4 c4 = *(const int4*)(sl + j + 8);
            int4 d4 = *(const int4*)(sl + j + 12);
            float t0 = b2f(hb[(a4.x << 6) + lane]);
            float t1 = b2f(hb[(a4.y << 6) + lane]);
            float t2 = b2f(hb[(a4.z << 6) + lane]);
            float t3 = b2f(hb[(a4.w << 6) + lane]);
            float t4 = b2f(hb[(b4.x << 6) + lane]);
            float t5 = b2f(hb[(b4.y << 6) + lane]);
            float t6 = b2f(hb[(b4.z << 6) + lane]);
            float t7 = b2f(hb[(b4.w << 6) + lane]);
            float t8 = b2f(hb[(c4.x << 6) + lane]);
            float t9 = b2f(hb[(c4.y << 6) + lane]);
            float ta = b2f(hb[(c4.z << 6) + lane]);
            float tb = b2f(hb[(c4.w << 6) + lane]);
            float tc = b2f(hb[(d4.x << 6) + lane]);
            float td = b2f(hb[(d4.y << 6) + lane]);
            float te = b2f(hb[(d4.z << 6) + lane]);
            float tf = b2f(hb[(d4.w << 6) + lane]);
            sum += ((t0 + t1) + (t2 + t3)) + ((t4 + t5) + (t6 + t7))
                 + ((t8 + t9) + (ta + tb)) + ((tc + td) + (te + tf));
        }
        s_a[nl][lane] = sum;
    }
    __syncthreads();

    const int c = lane, r = wave;
    float psum = 0.f;
    int cur_g = -1;
    for (int i = 0; i < 16; ++i) {
        int nl = r * 16 + i;
        int n = base + nl;
        if (n >= N_NODES) break;
        float acc = 0.f;
        #pragma unroll
        for (int k = 0; k < HID; k += 4) {
            float4 av = *(const float4*)&s_a[nl][k];
            acc += av.x * s_wrel[(k + 0) * HID + c] + av.y * s_wrel[(k + 1) * HID + c]
                 + av.z * s_wrel[(k + 2) * HID + c] + av.w * s_wrel[(k + 3) * HID + c];
        }
        int g = batch[n];
        if (g != cur_g) {
            if (cur_g >= 0) atomicAdd(&pooled_rel[(cur_g << 6) + c], psum);
            psum = 0.f;
            cur_g = g;
        }
        psum += acc;
    }
    if (cur_g >= 0) atomicAdd(&pooled_rel[(cur_g << 6) + c], psum);
}

// ---------------------------------------------------------------------------
// out[g][c] = relu( (pooled_rel + hsum@w2_root + cnt*b2) / max(cnt,1) )
// ---------------------------------------------------------------------------
__global__ void finalize_kernel(const float* __restrict__ pooled_rel,
                                const float* __restrict__ hsum,
                                const float* __restrict__ w2_root,
                                const float* __restrict__ b2,
                                const int* __restrict__ batch,
                                float* __restrict__ out) {
    __shared__ float s_h[HID];
    const int g = blockIdx.x;
    const int c = threadIdx.x;
    s_h[c] = hsum[(g << 6) + c];
    __syncthreads();

    int lo = 0, hi = N_NODES;
    while (lo < hi) { int m = (lo + hi) >> 1; if (batch[m] < g) lo = m + 1; else hi = m; }
    int start = lo;
    hi = N_NODES;
    while (lo < hi) { int m = (lo + hi) >> 1; if (batch[m] < g + 1) lo = m + 1; else hi = m; }
    int cntg = lo - start;

    float acc = pooled_rel[(g << 6) + c] + (float)cntg * b2[c];
    #pragma unroll
    for (int k = 0; k < HID; ++k) acc += s_h[k] * w2_root[k * HID + c];
    float denom = cntg > 0 ? (float)cntg : 1.f;
    out[(g << 6) + c] = fmaxf(acc / denom, 0.f);
}

// ---------------------------------------------------------------------------
extern "C" void kernel_launch(void* const* d_in, const int* in_sizes, int n_in,
                              void* d_out, int out_size, void* d_ws, size_t ws_size,
                              hipStream_t stream) {
    const float* x       = (const float*)d_in[0];
    const int*   ei      = (const int*)  d_in[1];
    const int*   batch   = (const int*)  d_in[2];
    const float* w1_rel  = (const float*)d_in[3];
    const float* b1_rel  = (const float*)d_in[4];
    const float* w1_root = (const float*)d_in[5];
    const float* w2_rel  = (const float*)d_in[6];
    const float* b2_rel  = (const float*)d_in[7];
    const float* w2_root = (const float*)d_in[8];
    float* out = (float*)d_out;

    const int* src = ei;
    const int* dst = ei + N_EDGES;

    // ws layout (bytes):
    //   [0,       400000)  cnt        N int          (zeroed)
    //   [400000,  465536)  hsum       256*64 f32     (zeroed)
    //   [465536,  531072)  pooled_rel 256*64 f32     (zeroed)
    //   [531072,  931072)  cntp       N int
    //   [931072, 26531072) slots      N*64 int       (16B-aligned)
    //   [26531072,34531152) xb        (N+1)*40 bf16
    //   [34531152,47331280) hb        (N+1)*64 bf16
    char* wsb = (char*)d_ws;
    int*    cnt        = (int*)   (wsb);
    float*  hsum       = (float*) (wsb + 400000);
    float*  pooled_rel = (float*) (wsb + 465536);
    int*    cntp       = (int*)   (wsb + 531072);
    int*    slots      = (int*)   (wsb + 931072);
    ushort* xb         = (ushort*)(wsb + 26531072);
    ushort* hb         = (ushort*)(wsb + 34531152);

    hipMemsetAsync(wsb, 0, 531072, stream);

    {   // pack x -> bf16 [N+1][40]
        int total = (N_NODES + 1) * F_PAD;
        pack_x_kernel<<<(total + 255) / 256, 256, 0, stream>>>(x, xb);
    }
    {   // CSR build
        csr_build_kernel<<<(N_EDGES + 255) / 256, 256, 0, stream>>>(src, dst, cnt, slots);
    }
    {   // pad slots to multiple of 16 with dummy; zero hb dummy row
        pad_slots_kernel<<<(N_NODES + 255) / 256, 256, 0, stream>>>(cnt, cntp, slots, hb);
    }
    {   // layer 1
        int blocks = (N_NODES + 63) / 64;
        layer1_kernel<<<blocks, 256, 0, stream>>>(x, xb, cntp, slots, w1_rel, b1_rel,
                                                  w1_root, batch, hb, hsum);
    }
    {   // layer 2 rel-half
        int blocks = (N_NODES + 63) / 64;
        layer2_kernel<<<blocks, 256, 0, stream>>>(hb, cntp, slots, w2_rel, batch,
                                                  pooled_rel);
    }
    {   // finalize
        finalize_kernel<<<N_GRAPHS, HID, 0, stream>>>(pooled_rel, hsum, w2_root,
                                                      b2_rel, batch, out);
    }
}